// Round 2
// baseline (192.045 us; speedup 1.0000x reference)
//
#include <hip/hip_runtime.h>

// BackwardRPM: 16384 independent solves, 200 steps of
//   u <- clip(u - LR * (R^T (R (tanh(u W1 + b1) W2 + b2 - spec)))[:6])
// Algebra: Qs = -LR * W2 R^T R[:, :6] (64x6), Ss = -LR * R[:, :6]^T R (6x40),
//   es = Ss (b2 - spec) per sample. Step: t = u W1 + b1; h = tanh(t);
//   u = clip(u + h Qs + es).
// Folds (R4): tanh(t) = 1 - 2*rcp(e^{2t}+1); pre-scale W1,b1 by K=2*log2(e)
//   so e^{2t} = exp2(uW1K + b1K); h Qs folded into per-thread consts with
//   Qs pre-scaled by -2.
// R5: asm-fused DPP butterfly (neutral -- was already fused), pair-rcp
//   (neutral). Lesson: loop is latency-bound at 2 waves/SIMD, not
//   issue-bound; instruction diet exhausted.
// R6 (this round):
//   (a) 16 lanes/sample (4 hidden units per lane) -> grid 4096 waves =
//       4 waves/SIMD. ~+18% issue demand (extra butterfly stage + dup'd
//       per-thread fixed work) bought for ~3x less VALU idle. Constants
//       halve -> ~100 VGPR fits the 128-reg/4-wave budget:
//       amdgpu_waves_per_eu(4,4).
//   (b) bit-exact early exit: if u_{t+1}==u_t bitwise for every sample in
//       the wave, remaining steps are identity -> break. Consecutive-step
//       compare (snapshot at step&15==14, test at ==15) avoids period-2
//       false exits. Uniform branch via __ballot.

static constexpr float LR_ = 0.01f;

typedef float v2f __attribute__((ext_vector_type(2)));

__device__ __forceinline__ void pin2(v2f& x) { asm volatile("" : "+v"(x)); }

__global__ __launch_bounds__(512)
__attribute__((amdgpu_waves_per_eu(4, 4)))
void solve_k(
    const float* __restrict__ spec, const float* __restrict__ W1,
    const float* __restrict__ b1,   const float* __restrict__ W2,
    const float* __restrict__ b2,   const float* __restrict__ R,
    float* __restrict__ out, int batch)
{
    __shared__ float sQs[64 * 7];  // Qs[i][j] = sQs[i*7+j] (stride 7: no 4-way bank conflict)
    __shared__ float sSs[240];     // Ss[j][k] = sSs[j*40+k] (includes -LR)

    const int t = threadIdx.x;

    // ---- per-block setup: Qs = -LR * W2 R^T R6, Ss = -LR * R6^T R ----
    if (t < 64) {
        float M[8];
        #pragma unroll
        for (int p = 0; p < 8; ++p) {
            float acc = 0.f;
            for (int k = 0; k < 40; ++k) acc = fmaf(W2[t*40+k], R[p*40+k], acc);
            M[p] = acc;
        }
        #pragma unroll
        for (int j = 0; j < 6; ++j) {
            float acc = 0.f;
            #pragma unroll
            for (int p = 0; p < 8; ++p) acc = fmaf(M[p], R[p*40+j], acc);
            sQs[t*7+j] = -LR_ * acc;
        }
    } else if (t >= 64 && t < 64 + 240) {
        int idx = t - 64;
        int j = idx / 40, k = idx % 40;
        float acc = 0.f;
        #pragma unroll
        for (int p = 0; p < 8; ++p) acc = fmaf(R[p*40+j], R[p*40+k], acc);
        sSs[idx] = -LR_ * acc;
    }
    __syncthreads();

    // ---- per-thread constants ----
    const int tid = blockIdx.x * 512 + t;
    const int s   = tid >> 4;    // sample
    const int sub = tid & 15;    // sixteenth of hidden dim
    const int ib  = sub * 4;     // 4 hidden units per lane
    const bool live = (s < batch);
    const int sl = live ? s : 0;

    const float K = 2.8853900817779268f;  // 2*log2(e)

    // W1 (6,64) row-major, pre-scaled by K, packed over hidden pairs.
    v2f w1kp[6][2], b1kp[2];
    #pragma unroll
    for (int j = 0; j < 6; ++j)
        #pragma unroll
        for (int ip = 0; ip < 2; ++ip) {
            w1kp[j][ip].x = K * W1[j*64 + ib + 2*ip];
            w1kp[j][ip].y = K * W1[j*64 + ib + 2*ip + 1];
        }
    #pragma unroll
    for (int ip = 0; ip < 2; ++ip) {
        b1kp[ip].x = K * b1[ib + 2*ip];
        b1kp[ip].y = K * b1[ib + 2*ip + 1];
    }

    // qs2p[i][m] = -2 * Qs[ib+i][2m..2m+1];  qc[j] = sum_i Qs[ib+i][j]
    v2f qs2p[4][3];
    float qc[6];
    #pragma unroll
    for (int j = 0; j < 6; ++j) qc[j] = 0.f;
    #pragma unroll
    for (int i = 0; i < 4; ++i)
        #pragma unroll
        for (int m = 0; m < 3; ++m) {
            float a = sQs[(ib + i)*7 + 2*m];
            float b = sQs[(ib + i)*7 + 2*m + 1];
            qs2p[i][m].x = -2.f * a;
            qs2p[i][m].y = -2.f * b;
            qc[2*m]   += a;
            qc[2*m+1] += b;
        }

    // es[j] = sum_k Ss[j][k]*(b2[k]-spec[k]);  c2[m] = es/16 + qc (packed)
    float es[6];
    #pragma unroll
    for (int j = 0; j < 6; ++j) es[j] = 0.f;
    const float* sp = spec + sl * 40;
    for (int k = 0; k < 40; ++k) {
        float v = b2[k] - sp[k];
        #pragma unroll
        for (int j = 0; j < 6; ++j) es[j] = fmaf(v, sSs[j*40+k], es[j]);
    }
    v2f c2[3];
    #pragma unroll
    for (int m = 0; m < 3; ++m) {
        c2[m].x = es[2*m]   * 0.0625f + qc[2*m];
        c2[m].y = es[2*m+1] * 0.0625f + qc[2*m+1];
    }

    // pin loop-invariants (belt+suspenders vs remat)
    #pragma unroll
    for (int j = 0; j < 6; ++j)
        #pragma unroll
        for (int ip = 0; ip < 2; ++ip) pin2(w1kp[j][ip]);
    #pragma unroll
    for (int ip = 0; ip < 2; ++ip) pin2(b1kp[ip]);
    #pragma unroll
    for (int i = 0; i < 4; ++i)
        #pragma unroll
        for (int m = 0; m < 3; ++m) pin2(qs2p[i][m]);
    #pragma unroll
    for (int m = 0; m < 3; ++m) pin2(c2[m]);

    float u[6], up[6];
    #pragma unroll
    for (int j = 0; j < 6; ++j) { u[j] = 0.5f; up[j] = -1.f; }

    for (int step = 0; step < 200; ++step) {
        // r_i = rcp(exp2(uW1K + b1K) + 1)   (tanh = 1 - 2r, folded into consts)
        // pair-rcp: ra = eb*rcp(ea*eb), rb = ea*rcp(ea*eb).
        float r[4];
        #pragma unroll
        for (int ip = 0; ip < 2; ++ip) {
            v2f tt = b1kp[ip];
            #pragma unroll
            for (int j = 0; j < 6; ++j) {
                v2f ub = {u[j], u[j]};
                tt = __builtin_elementwise_fma(ub, w1kp[j][ip], tt);
            }
            v2f e1;
            e1.x = __builtin_amdgcn_exp2f(tt.x);
            e1.y = __builtin_amdgcn_exp2f(tt.y);
            e1 += (v2f){1.f, 1.f};
            float rab = __builtin_amdgcn_rcpf(e1.x * e1.y);
            r[2*ip]   = e1.y * rab;
            r[2*ip+1] = e1.x * rab;
        }
        // per-lane partial: g = u/16 + c + sum_i r_i * (-2 Qs[i,:])
        v2f g2[3];
        #pragma unroll
        for (int m = 0; m < 3; ++m) {
            v2f up2 = {u[2*m], u[2*m+1]};
            g2[m] = __builtin_elementwise_fma(up2, (v2f){0.0625f, 0.0625f}, c2[m]);
        }
        #pragma unroll
        for (int i = 0; i < 4; ++i) {
            v2f hb = {r[i], r[i]};
            #pragma unroll
            for (int m = 0; m < 3; ++m)
                g2[m] = __builtin_elementwise_fma(hb, qs2p[i][m], g2[m]);
        }
        // allreduce over 16 lanes: xor1, xor2, xor7(~xor4), xor15(~xor8).
        // Single asm block of fused v_add_f32_dpp; 6 chains interleaved so
        // each dependent pair has 5 intervening instrs (>= 2 wait states
        // req'd for VALU->DPP). s_nop 1 covers the compiler's last pk_fma.
        float a0 = g2[0].x, a1 = g2[0].y, a2 = g2[1].x,
              a3 = g2[1].y, a4 = g2[2].x, a5 = g2[2].y;
        asm("s_nop 1\n\t"
            "v_add_f32_dpp %0, %0, %0 quad_perm:[1,0,3,2] row_mask:0xf bank_mask:0xf bound_ctrl:0\n\t"
            "v_add_f32_dpp %1, %1, %1 quad_perm:[1,0,3,2] row_mask:0xf bank_mask:0xf bound_ctrl:0\n\t"
            "v_add_f32_dpp %2, %2, %2 quad_perm:[1,0,3,2] row_mask:0xf bank_mask:0xf bound_ctrl:0\n\t"
            "v_add_f32_dpp %3, %3, %3 quad_perm:[1,0,3,2] row_mask:0xf bank_mask:0xf bound_ctrl:0\n\t"
            "v_add_f32_dpp %4, %4, %4 quad_perm:[1,0,3,2] row_mask:0xf bank_mask:0xf bound_ctrl:0\n\t"
            "v_add_f32_dpp %5, %5, %5 quad_perm:[1,0,3,2] row_mask:0xf bank_mask:0xf bound_ctrl:0\n\t"
            "v_add_f32_dpp %0, %0, %0 quad_perm:[2,3,0,1] row_mask:0xf bank_mask:0xf bound_ctrl:0\n\t"
            "v_add_f32_dpp %1, %1, %1 quad_perm:[2,3,0,1] row_mask:0xf bank_mask:0xf bound_ctrl:0\n\t"
            "v_add_f32_dpp %2, %2, %2 quad_perm:[2,3,0,1] row_mask:0xf bank_mask:0xf bound_ctrl:0\n\t"
            "v_add_f32_dpp %3, %3, %3 quad_perm:[2,3,0,1] row_mask:0xf bank_mask:0xf bound_ctrl:0\n\t"
            "v_add_f32_dpp %4, %4, %4 quad_perm:[2,3,0,1] row_mask:0xf bank_mask:0xf bound_ctrl:0\n\t"
            "v_add_f32_dpp %5, %5, %5 quad_perm:[2,3,0,1] row_mask:0xf bank_mask:0xf bound_ctrl:0\n\t"
            "v_add_f32_dpp %0, %0, %0 row_half_mirror row_mask:0xf bank_mask:0xf bound_ctrl:0\n\t"
            "v_add_f32_dpp %1, %1, %1 row_half_mirror row_mask:0xf bank_mask:0xf bound_ctrl:0\n\t"
            "v_add_f32_dpp %2, %2, %2 row_half_mirror row_mask:0xf bank_mask:0xf bound_ctrl:0\n\t"
            "v_add_f32_dpp %3, %3, %3 row_half_mirror row_mask:0xf bank_mask:0xf bound_ctrl:0\n\t"
            "v_add_f32_dpp %4, %4, %4 row_half_mirror row_mask:0xf bank_mask:0xf bound_ctrl:0\n\t"
            "v_add_f32_dpp %5, %5, %5 row_half_mirror row_mask:0xf bank_mask:0xf bound_ctrl:0\n\t"
            "v_add_f32_dpp %0, %0, %0 row_mirror row_mask:0xf bank_mask:0xf bound_ctrl:0\n\t"
            "v_add_f32_dpp %1, %1, %1 row_mirror row_mask:0xf bank_mask:0xf bound_ctrl:0\n\t"
            "v_add_f32_dpp %2, %2, %2 row_mirror row_mask:0xf bank_mask:0xf bound_ctrl:0\n\t"
            "v_add_f32_dpp %3, %3, %3 row_mirror row_mask:0xf bank_mask:0xf bound_ctrl:0\n\t"
            "v_add_f32_dpp %4, %4, %4 row_mirror row_mask:0xf bank_mask:0xf bound_ctrl:0\n\t"
            "v_add_f32_dpp %5, %5, %5 row_mirror row_mask:0xf bank_mask:0xf bound_ctrl:0\n\t"
            : "+v"(a0), "+v"(a1), "+v"(a2), "+v"(a3), "+v"(a4), "+v"(a5));
        u[0] = __builtin_amdgcn_fmed3f(a0, 0.f, 1.f);
        u[1] = __builtin_amdgcn_fmed3f(a1, 0.f, 1.f);
        u[2] = __builtin_amdgcn_fmed3f(a2, 0.f, 1.f);
        u[3] = __builtin_amdgcn_fmed3f(a3, 0.f, 1.f);
        u[4] = __builtin_amdgcn_fmed3f(a4, 0.f, 1.f);
        u[5] = __builtin_amdgcn_fmed3f(a5, 0.f, 1.f);

        // bit-exact early exit: u_{t+1}==u_t => all remaining steps identity.
        // Snapshot at phase 14, compare consecutive steps at phase 15.
        int ph = step & 15;
        if (ph == 14) {
            #pragma unroll
            for (int j = 0; j < 6; ++j) up[j] = u[j];
        } else if (ph == 15) {
            bool ch = (u[0] != up[0]) | (u[1] != up[1]) | (u[2] != up[2]) |
                      (u[3] != up[3]) | (u[4] != up[4]) | (u[5] != up[5]);
            if (__ballot(ch) == 0ull) break;
        }
    }

    if (live && sub == 0) {
        float* o = out + s * 6;
        #pragma unroll
        for (int j = 0; j < 6; ++j) o[j] = u[j];
    }
}

extern "C" void kernel_launch(void* const* d_in, const int* in_sizes, int n_in,
                              void* d_out, int out_size, void* d_ws, size_t ws_size,
                              hipStream_t stream)
{
    const float* spec = (const float*)d_in[0];  // (B,40)
    const float* W1   = (const float*)d_in[1];  // (6,64)
    const float* b1   = (const float*)d_in[2];  // (64,)
    const float* W2   = (const float*)d_in[3];  // (64,40)
    const float* b2   = (const float*)d_in[4];  // (40,)
    const float* R    = (const float*)d_in[5];  // (8,40)
    int batch = in_sizes[0] / 40;

    int threads = batch * 16;
    int blocks  = (threads + 511) / 512;
    hipLaunchKernelGGL(solve_k, dim3(blocks), dim3(512), 0, stream,
                       spec, W1, b1, W2, b2, R, (float*)d_out, batch);
}

// Round 3
// 156.471 us; speedup vs baseline: 1.2274x; 1.2274x over previous
//
#include <hip/hip_runtime.h>

// BackwardRPM: 16384 independent solves, 200 steps of
//   u <- clip(u - LR * (R^T (R (tanh(u W1 + b1) W2 + b2 - spec)))[:6])
// Algebra: Qs = -LR * W2 R^T R[:, :6] (64x6), Ss = -LR * R[:, :6]^T R (6x40),
//   es = Ss (b2 - spec) per sample. Step: t = u W1 + b1; h = tanh(t);
//   u = clip(u + h Qs + es).
// Folds (R4): tanh(t) = 1 - 2*rcp(e^{2t}+1); pre-scale W1,b1 by K=2*log2(e)
//   so e^{2t} = exp2(uW1K + b1K); h Qs folded into per-thread consts with
//   Qs pre-scaled by -2.
// R5: asm DPP butterfly (neutral: was already fused), pair-rcp (neutral).
// R6: 16 lanes/sample for 4 waves/SIMD -> REGRESSED 116->151us. Per-sample
//   issue work grew 40% (fixed per-lane overhead amortized over half the
//   samples); VALUBusy only 71->78. Kernel is issue-bound, not
//   latency-bound. Early-exit never fired. Lesson: L=8 is the sweet spot.
// R7 (this round), back on the L=8 structure:
//   (a) u and r kept as packed v2f; broadcasts done with inline-asm VOP3P
//       op_sel (lo: op_sel:[0,0,0] op_sel_hi:[0,1,1]; hi: op_sel:[1,0,0]
//       op_sel_hi:[1,1,1]) -> zero splat v_movs.
//   (b) g-accumulation split into two parallel chains (depth 9 -> 5);
//       the 6 combining scalar adds produce the butterfly inputs directly.
//   (c) pair-rcp reverted (plain 8 rcp: fewer main-pipe VALU ops, trans
//       pipe is under-subscribed); early-exit removed.

static constexpr float LR_ = 0.01f;

typedef float v2f __attribute__((ext_vector_type(2)));

__device__ __forceinline__ void pin2(v2f& x) { asm volatile("" : "+v"(x)); }

// v_pk_fma_f32 with src0 broadcast from lo/hi half (VOP3P op_sel).
#define PK_FMA_LO(T, U, W)                                                   \
    asm("v_pk_fma_f32 %0, %1, %2, %0 op_sel:[0,0,0] op_sel_hi:[0,1,1]"       \
        : "+v"(T) : "v"(U), "v"(W))
#define PK_FMA_HI(T, U, W)                                                   \
    asm("v_pk_fma_f32 %0, %1, %2, %0 op_sel:[1,0,0] op_sel_hi:[1,1,1]"       \
        : "+v"(T) : "v"(U), "v"(W))
#define PK_MUL_LO(D, U, W)                                                   \
    asm("v_pk_mul_f32 %0, %1, %2 op_sel:[0,0] op_sel_hi:[0,1]"               \
        : "=v"(D) : "v"(U), "v"(W))

__global__ __launch_bounds__(256)
__attribute__((amdgpu_waves_per_eu(2, 2)))
void solve_k(
    const float* __restrict__ spec, const float* __restrict__ W1,
    const float* __restrict__ b1,   const float* __restrict__ W2,
    const float* __restrict__ b2,   const float* __restrict__ R,
    float* __restrict__ out, int batch)
{
    __shared__ float sQs[64 * 7];  // Qs[i][j] = sQs[i*7+j] (stride 7: no 4-way bank conflict)
    __shared__ float sSs[240];     // Ss[j][k] = sSs[j*40+k] (includes -LR)

    const int t = threadIdx.x;

    // ---- per-block setup: Qs = -LR * W2 R^T R6, Ss = -LR * R6^T R ----
    if (t < 64) {
        float M[8];
        #pragma unroll
        for (int p = 0; p < 8; ++p) {
            float acc = 0.f;
            for (int k = 0; k < 40; ++k) acc = fmaf(W2[t*40+k], R[p*40+k], acc);
            M[p] = acc;
        }
        #pragma unroll
        for (int j = 0; j < 6; ++j) {
            float acc = 0.f;
            #pragma unroll
            for (int p = 0; p < 8; ++p) acc = fmaf(M[p], R[p*40+j], acc);
            sQs[t*7+j] = -LR_ * acc;
        }
    } else {
        for (int idx = t - 64; idx < 240; idx += 192) {
            int j = idx / 40, k = idx % 40;
            float acc = 0.f;
            #pragma unroll
            for (int p = 0; p < 8; ++p) acc = fmaf(R[p*40+j], R[p*40+k], acc);
            sSs[idx] = -LR_ * acc;
        }
    }
    __syncthreads();

    // ---- per-thread constants ----
    const int tid = blockIdx.x * 256 + t;
    const int s   = tid >> 3;    // sample
    const int sub = tid & 7;     // eighth of hidden dim
    const int ib  = sub * 8;
    const bool live = (s < batch);
    const int sl = live ? s : 0;

    const float K = 2.8853900817779268f;  // 2*log2(e)

    // W1 (6,64) row-major, pre-scaled by K, packed over hidden pairs.
    v2f w1kp[6][4], b1kp[4];
    #pragma unroll
    for (int j = 0; j < 6; ++j)
        #pragma unroll
        for (int ip = 0; ip < 4; ++ip) {
            w1kp[j][ip].x = K * W1[j*64 + ib + 2*ip];
            w1kp[j][ip].y = K * W1[j*64 + ib + 2*ip + 1];
        }
    #pragma unroll
    for (int ip = 0; ip < 4; ++ip) {
        b1kp[ip].x = K * b1[ib + 2*ip];
        b1kp[ip].y = K * b1[ib + 2*ip + 1];
    }

    // qs2p[i][m] = -2 * Qs[ib+i][2m..2m+1];  qc[j] = sum_i Qs[ib+i][j]
    v2f qs2p[8][3];
    float qc[6];
    #pragma unroll
    for (int j = 0; j < 6; ++j) qc[j] = 0.f;
    #pragma unroll
    for (int i = 0; i < 8; ++i)
        #pragma unroll
        for (int m = 0; m < 3; ++m) {
            float a = sQs[(ib + i)*7 + 2*m];
            float b = sQs[(ib + i)*7 + 2*m + 1];
            qs2p[i][m].x = -2.f * a;
            qs2p[i][m].y = -2.f * b;
            qc[2*m]   += a;
            qc[2*m+1] += b;
        }

    // es[j] = sum_k Ss[j][k]*(b2[k]-spec[k]);  c2[m] = es/8 + qc (packed)
    float es[6];
    #pragma unroll
    for (int j = 0; j < 6; ++j) es[j] = 0.f;
    const float* sp = spec + sl * 40;
    for (int k = 0; k < 40; ++k) {
        float v = b2[k] - sp[k];
        #pragma unroll
        for (int j = 0; j < 6; ++j) es[j] = fmaf(v, sSs[j*40+k], es[j]);
    }
    v2f c2[3];
    #pragma unroll
    for (int m = 0; m < 3; ++m) {
        c2[m].x = es[2*m]   * 0.125f + qc[2*m];
        c2[m].y = es[2*m+1] * 0.125f + qc[2*m+1];
    }

    v2f eighth = {0.125f, 0.125f};

    // pin loop-invariants (belt+suspenders vs remat; budget is 256 VGPRs)
    #pragma unroll
    for (int j = 0; j < 6; ++j)
        #pragma unroll
        for (int ip = 0; ip < 4; ++ip) pin2(w1kp[j][ip]);
    #pragma unroll
    for (int ip = 0; ip < 4; ++ip) pin2(b1kp[ip]);
    #pragma unroll
    for (int i = 0; i < 8; ++i)
        #pragma unroll
        for (int m = 0; m < 3; ++m) pin2(qs2p[i][m]);
    #pragma unroll
    for (int m = 0; m < 3; ++m) pin2(c2[m]);
    pin2(eighth);

    // u kept packed: u2[m] = {u[2m], u[2m+1]}
    v2f u2[3];
    #pragma unroll
    for (int m = 0; m < 3; ++m) u2[m] = (v2f){0.5f, 0.5f};

    for (int step = 0; step < 200; ++step) {
        // tt[ip] = b1K + sum_j u[j]*W1K[j] over this lane's hidden pairs.
        // Broadcast u via VOP3P op_sel -- no splat movs.
        v2f tt0 = b1kp[0], tt1 = b1kp[1], tt2 = b1kp[2], tt3 = b1kp[3];
        #pragma unroll
        for (int jp = 0; jp < 3; ++jp) {
            PK_FMA_LO(tt0, u2[jp], w1kp[2*jp][0]);
            PK_FMA_LO(tt1, u2[jp], w1kp[2*jp][1]);
            PK_FMA_LO(tt2, u2[jp], w1kp[2*jp][2]);
            PK_FMA_LO(tt3, u2[jp], w1kp[2*jp][3]);
            PK_FMA_HI(tt0, u2[jp], w1kp[2*jp+1][0]);
            PK_FMA_HI(tt1, u2[jp], w1kp[2*jp+1][1]);
            PK_FMA_HI(tt2, u2[jp], w1kp[2*jp+1][2]);
            PK_FMA_HI(tt3, u2[jp], w1kp[2*jp+1][3]);
        }
        // r2[ip] = rcp(exp2(tt) + 1), packed (tanh = 1-2r folded into consts)
        v2f r2[4];
        {
            v2f e0, e1, e2, e3;
            e0.x = __builtin_amdgcn_exp2f(tt0.x); e0.y = __builtin_amdgcn_exp2f(tt0.y);
            e1.x = __builtin_amdgcn_exp2f(tt1.x); e1.y = __builtin_amdgcn_exp2f(tt1.y);
            e2.x = __builtin_amdgcn_exp2f(tt2.x); e2.y = __builtin_amdgcn_exp2f(tt2.y);
            e3.x = __builtin_amdgcn_exp2f(tt3.x); e3.y = __builtin_amdgcn_exp2f(tt3.y);
            e0 += (v2f){1.f, 1.f}; e1 += (v2f){1.f, 1.f};
            e2 += (v2f){1.f, 1.f}; e3 += (v2f){1.f, 1.f};
            r2[0].x = __builtin_amdgcn_rcpf(e0.x); r2[0].y = __builtin_amdgcn_rcpf(e0.y);
            r2[1].x = __builtin_amdgcn_rcpf(e1.x); r2[1].y = __builtin_amdgcn_rcpf(e1.y);
            r2[2].x = __builtin_amdgcn_rcpf(e2.x); r2[2].y = __builtin_amdgcn_rcpf(e2.y);
            r2[3].x = __builtin_amdgcn_rcpf(e3.x); r2[3].y = __builtin_amdgcn_rcpf(e3.y);
        }
        // g = u/8 + c2 + sum_i r_i * (-2 Qs[i,:]), split into two chains:
        // gA: units 0..3 (init = u/8 + c2), gB: units 4..7 (init = mul).
        v2f gA0, gA1, gA2, gB0, gB1, gB2;
        gA0 = __builtin_elementwise_fma(u2[0], eighth, c2[0]);
        gA1 = __builtin_elementwise_fma(u2[1], eighth, c2[1]);
        gA2 = __builtin_elementwise_fma(u2[2], eighth, c2[2]);
        PK_MUL_LO(gB0, r2[2], qs2p[4][0]);
        PK_MUL_LO(gB1, r2[2], qs2p[4][1]);
        PK_MUL_LO(gB2, r2[2], qs2p[4][2]);
        PK_FMA_LO(gA0, r2[0], qs2p[0][0]);
        PK_FMA_LO(gA1, r2[0], qs2p[0][1]);
        PK_FMA_LO(gA2, r2[0], qs2p[0][2]);
        PK_FMA_HI(gB0, r2[2], qs2p[5][0]);
        PK_FMA_HI(gB1, r2[2], qs2p[5][1]);
        PK_FMA_HI(gB2, r2[2], qs2p[5][2]);
        PK_FMA_HI(gA0, r2[0], qs2p[1][0]);
        PK_FMA_HI(gA1, r2[0], qs2p[1][1]);
        PK_FMA_HI(gA2, r2[0], qs2p[1][2]);
        PK_FMA_LO(gB0, r2[3], qs2p[6][0]);
        PK_FMA_LO(gB1, r2[3], qs2p[6][1]);
        PK_FMA_LO(gB2, r2[3], qs2p[6][2]);
        PK_FMA_LO(gA0, r2[1], qs2p[2][0]);
        PK_FMA_LO(gA1, r2[1], qs2p[2][1]);
        PK_FMA_LO(gA2, r2[1], qs2p[2][2]);
        PK_FMA_HI(gB0, r2[3], qs2p[7][0]);
        PK_FMA_HI(gB1, r2[3], qs2p[7][1]);
        PK_FMA_HI(gB2, r2[3], qs2p[7][2]);
        PK_FMA_HI(gA0, r2[1], qs2p[3][0]);
        PK_FMA_HI(gA1, r2[1], qs2p[3][1]);
        PK_FMA_HI(gA2, r2[1], qs2p[3][2]);
        // combine halves -> 6 scalars (these are the butterfly inputs)
        float a0 = gA0.x + gB0.x, a1 = gA0.y + gB0.y;
        float a2 = gA1.x + gB1.x, a3 = gA1.y + gB1.y;
        float a4 = gA2.x + gB2.x, a5 = gA2.y + gB2.y;
        // allreduce over 8 lanes: xor1, xor2, xor7. Fused v_add_f32_dpp;
        // 6 chains interleaved -> >=5 instrs between dependent stages
        // (VALU->DPP needs 2 wait states). s_nop 1 covers the last add.
        asm("s_nop 1\n\t"
            "v_add_f32_dpp %0, %0, %0 quad_perm:[1,0,3,2] row_mask:0xf bank_mask:0xf bound_ctrl:0\n\t"
            "v_add_f32_dpp %1, %1, %1 quad_perm:[1,0,3,2] row_mask:0xf bank_mask:0xf bound_ctrl:0\n\t"
            "v_add_f32_dpp %2, %2, %2 quad_perm:[1,0,3,2] row_mask:0xf bank_mask:0xf bound_ctrl:0\n\t"
            "v_add_f32_dpp %3, %3, %3 quad_perm:[1,0,3,2] row_mask:0xf bank_mask:0xf bound_ctrl:0\n\t"
            "v_add_f32_dpp %4, %4, %4 quad_perm:[1,0,3,2] row_mask:0xf bank_mask:0xf bound_ctrl:0\n\t"
            "v_add_f32_dpp %5, %5, %5 quad_perm:[1,0,3,2] row_mask:0xf bank_mask:0xf bound_ctrl:0\n\t"
            "v_add_f32_dpp %0, %0, %0 quad_perm:[2,3,0,1] row_mask:0xf bank_mask:0xf bound_ctrl:0\n\t"
            "v_add_f32_dpp %1, %1, %1 quad_perm:[2,3,0,1] row_mask:0xf bank_mask:0xf bound_ctrl:0\n\t"
            "v_add_f32_dpp %2, %2, %2 quad_perm:[2,3,0,1] row_mask:0xf bank_mask:0xf bound_ctrl:0\n\t"
            "v_add_f32_dpp %3, %3, %3 quad_perm:[2,3,0,1] row_mask:0xf bank_mask:0xf bound_ctrl:0\n\t"
            "v_add_f32_dpp %4, %4, %4 quad_perm:[2,3,0,1] row_mask:0xf bank_mask:0xf bound_ctrl:0\n\t"
            "v_add_f32_dpp %5, %5, %5 quad_perm:[2,3,0,1] row_mask:0xf bank_mask:0xf bound_ctrl:0\n\t"
            "v_add_f32_dpp %0, %0, %0 row_half_mirror row_mask:0xf bank_mask:0xf bound_ctrl:0\n\t"
            "v_add_f32_dpp %1, %1, %1 row_half_mirror row_mask:0xf bank_mask:0xf bound_ctrl:0\n\t"
            "v_add_f32_dpp %2, %2, %2 row_half_mirror row_mask:0xf bank_mask:0xf bound_ctrl:0\n\t"
            "v_add_f32_dpp %3, %3, %3 row_half_mirror row_mask:0xf bank_mask:0xf bound_ctrl:0\n\t"
            "v_add_f32_dpp %4, %4, %4 row_half_mirror row_mask:0xf bank_mask:0xf bound_ctrl:0\n\t"
            "v_add_f32_dpp %5, %5, %5 row_half_mirror row_mask:0xf bank_mask:0xf bound_ctrl:0\n\t"
            : "+v"(a0), "+v"(a1), "+v"(a2), "+v"(a3), "+v"(a4), "+v"(a5));
        u2[0].x = __builtin_amdgcn_fmed3f(a0, 0.f, 1.f);
        u2[0].y = __builtin_amdgcn_fmed3f(a1, 0.f, 1.f);
        u2[1].x = __builtin_amdgcn_fmed3f(a2, 0.f, 1.f);
        u2[1].y = __builtin_amdgcn_fmed3f(a3, 0.f, 1.f);
        u2[2].x = __builtin_amdgcn_fmed3f(a4, 0.f, 1.f);
        u2[2].y = __builtin_amdgcn_fmed3f(a5, 0.f, 1.f);
    }

    if (live && sub == 0) {
        float* o = out + s * 6;
        o[0] = u2[0].x; o[1] = u2[0].y;
        o[2] = u2[1].x; o[3] = u2[1].y;
        o[4] = u2[2].x; o[5] = u2[2].y;
    }
}

extern "C" void kernel_launch(void* const* d_in, const int* in_sizes, int n_in,
                              void* d_out, int out_size, void* d_ws, size_t ws_size,
                              hipStream_t stream)
{
    const float* spec = (const float*)d_in[0];  // (B,40)
    const float* W1   = (const float*)d_in[1];  // (6,64)
    const float* b1   = (const float*)d_in[2];  // (64,)
    const float* W2   = (const float*)d_in[3];  // (64,40)
    const float* b2   = (const float*)d_in[4];  // (40,)
    const float* R    = (const float*)d_in[5];  // (8,40)
    int batch = in_sizes[0] / 40;

    int threads = batch * 8;
    int blocks  = (threads + 255) / 256;
    hipLaunchKernelGGL(solve_k, dim3(blocks), dim3(256), 0, stream,
                       spec, W1, b1, W2, b2, R, (float*)d_out, batch);
}

// Round 4
// 144.181 us; speedup vs baseline: 1.3320x; 1.0852x over previous
//
#include <hip/hip_runtime.h>

// BackwardRPM: 16384 independent solves, 200 steps of
//   u <- clip(u - LR * (R^T (R (tanh(u W1 + b1) W2 + b2 - spec)))[:6])
// Algebra: Qs = -LR * W2 R^T R[:, :6] (64x6), Ss = -LR * R[:, :6]^T R (6x40),
//   es = Ss (b2 - spec) per sample. Step: t = u W1 + b1; h = tanh(t);
//   u = clip(u + h Qs + es).
// Folds (R4): tanh(t) = 1 - 2*rcp(e^{2t}+1); pre-scale W1,b1 by K=2*log2(e)
//   so e^{2t} = exp2(uW1K + b1K); h Qs folded into per-thread consts with
//   Qs pre-scaled by -2.
// R5: asm DPP butterfly (neutral: was already fused), pair-rcp (neutral).
// R6: L=16 lanes/sample -> REGRESSED (per-sample issue demand +25-40%).
// R7: op_sel broadcasts + split g-chains: 116.5 -> 110.9us. Calibrated
//   model: v_pk_fma_f32 = 4cy/wave64 (packed fp32 == scalar fp32 ALU
//   throughput; packing saves issue slots only). Static demand now matches
//   measured busy within ~10%.
// R8 (this round): L=4 lanes/sample (16 hidden units/lane, 16 samples/wave).
//   Reduce shrinks to 2 quad_perm DPP stages + combine; per-sample demand
//   53cy vs 64cy at L=8 (-17%). Cost: grid = 1024 waves = 1 wave/SIMD --
//   all stalls exposed; body has wide ILP (8 tt chains, 16 indep trans,
//   2 g chains) so predicted exposure ~15-25%. Constants ~270 VGPR ->
//   amdgpu_waves_per_eu(1,1) for the full 512-reg budget.

static constexpr float LR_ = 0.01f;

typedef float v2f __attribute__((ext_vector_type(2)));

__device__ __forceinline__ void pin2(v2f& x) { asm volatile("" : "+v"(x)); }

// v_pk_fma_f32 with src0 broadcast from lo/hi half (VOP3P op_sel).
#define PK_FMA_LO(T, U, W)                                                   \
    asm("v_pk_fma_f32 %0, %1, %2, %0 op_sel:[0,0,0] op_sel_hi:[0,1,1]"       \
        : "+v"(T) : "v"(U), "v"(W))
#define PK_FMA_HI(T, U, W)                                                   \
    asm("v_pk_fma_f32 %0, %1, %2, %0 op_sel:[1,0,0] op_sel_hi:[1,1,1]"       \
        : "+v"(T) : "v"(U), "v"(W))
#define PK_MUL_LO(D, U, W)                                                   \
    asm("v_pk_mul_f32 %0, %1, %2 op_sel:[0,0] op_sel_hi:[0,1]"               \
        : "=v"(D) : "v"(U), "v"(W))
#define PK_MUL_HI(D, U, W)                                                   \
    asm("v_pk_mul_f32 %0, %1, %2 op_sel:[1,0] op_sel_hi:[1,1]"               \
        : "=v"(D) : "v"(U), "v"(W))

__global__ __launch_bounds__(256)
__attribute__((amdgpu_waves_per_eu(1, 1)))
void solve_k(
    const float* __restrict__ spec, const float* __restrict__ W1,
    const float* __restrict__ b1,   const float* __restrict__ W2,
    const float* __restrict__ b2,   const float* __restrict__ R,
    float* __restrict__ out, int batch)
{
    __shared__ float sQs[64 * 7];  // Qs[i][j] = sQs[i*7+j]
    __shared__ float sSs[240];     // Ss[j][k] = sSs[j*40+k] (includes -LR)

    const int t = threadIdx.x;

    // ---- per-block setup: Qs = -LR * W2 R^T R6, Ss = -LR * R6^T R ----
    if (t < 64) {
        float M[8];
        #pragma unroll
        for (int p = 0; p < 8; ++p) {
            float acc = 0.f;
            for (int k = 0; k < 40; ++k) acc = fmaf(W2[t*40+k], R[p*40+k], acc);
            M[p] = acc;
        }
        #pragma unroll
        for (int j = 0; j < 6; ++j) {
            float acc = 0.f;
            #pragma unroll
            for (int p = 0; p < 8; ++p) acc = fmaf(M[p], R[p*40+j], acc);
            sQs[t*7+j] = -LR_ * acc;
        }
    } else {
        for (int idx = t - 64; idx < 240; idx += 192) {
            int j = idx / 40, k = idx % 40;
            float acc = 0.f;
            #pragma unroll
            for (int p = 0; p < 8; ++p) acc = fmaf(R[p*40+j], R[p*40+k], acc);
            sSs[idx] = -LR_ * acc;
        }
    }
    __syncthreads();

    // ---- per-thread constants ----
    const int tid = blockIdx.x * 256 + t;
    const int s   = tid >> 2;    // sample (16 per wave, one per quad)
    const int sub = tid & 3;     // quarter of hidden dim
    const int ib  = sub * 16;    // 16 hidden units per lane
    const bool live = (s < batch);
    const int sl = live ? s : 0;

    const float K = 2.8853900817779268f;  // 2*log2(e)

    // W1 (6,64) row-major, pre-scaled by K, packed over hidden pairs p=0..7.
    v2f w1kp[6][8], b1kp[8];
    #pragma unroll
    for (int j = 0; j < 6; ++j)
        #pragma unroll
        for (int p = 0; p < 8; ++p) {
            w1kp[j][p].x = K * W1[j*64 + ib + 2*p];
            w1kp[j][p].y = K * W1[j*64 + ib + 2*p + 1];
        }
    #pragma unroll
    for (int p = 0; p < 8; ++p) {
        b1kp[p].x = K * b1[ib + 2*p];
        b1kp[p].y = K * b1[ib + 2*p + 1];
    }

    // qs2p[i][m] = -2 * Qs[ib+i][2m..2m+1];  qc[j] = sum_i Qs[ib+i][j]
    v2f qs2p[16][3];
    float qc[6];
    #pragma unroll
    for (int j = 0; j < 6; ++j) qc[j] = 0.f;
    #pragma unroll
    for (int i = 0; i < 16; ++i)
        #pragma unroll
        for (int m = 0; m < 3; ++m) {
            float a = sQs[(ib + i)*7 + 2*m];
            float b = sQs[(ib + i)*7 + 2*m + 1];
            qs2p[i][m].x = -2.f * a;
            qs2p[i][m].y = -2.f * b;
            qc[2*m]   += a;
            qc[2*m+1] += b;
        }

    // es[j] = sum_k Ss[j][k]*(b2[k]-spec[k]);  c2[m] = es/4 + qc (packed)
    float es[6];
    #pragma unroll
    for (int j = 0; j < 6; ++j) es[j] = 0.f;
    const float* sp = spec + sl * 40;
    for (int k = 0; k < 40; ++k) {
        float v = b2[k] - sp[k];
        #pragma unroll
        for (int j = 0; j < 6; ++j) es[j] = fmaf(v, sSs[j*40+k], es[j]);
    }
    v2f c2[3];
    #pragma unroll
    for (int m = 0; m < 3; ++m) {
        c2[m].x = es[2*m]   * 0.25f + qc[2*m];
        c2[m].y = es[2*m+1] * 0.25f + qc[2*m+1];
    }

    v2f quarter = {0.25f, 0.25f};

    // pin loop-invariants (belt+suspenders vs remat; budget is 512 VGPRs)
    #pragma unroll
    for (int j = 0; j < 6; ++j)
        #pragma unroll
        for (int p = 0; p < 8; ++p) pin2(w1kp[j][p]);
    #pragma unroll
    for (int p = 0; p < 8; ++p) pin2(b1kp[p]);
    #pragma unroll
    for (int i = 0; i < 16; ++i)
        #pragma unroll
        for (int m = 0; m < 3; ++m) pin2(qs2p[i][m]);
    #pragma unroll
    for (int m = 0; m < 3; ++m) pin2(c2[m]);
    pin2(quarter);

    // u kept packed: u2[m] = {u[2m], u[2m+1]}
    v2f u2[3];
    #pragma unroll
    for (int m = 0; m < 3; ++m) u2[m] = (v2f){0.5f, 0.5f};

    for (int step = 0; step < 200; ++step) {
        // tt[p] = b1K + sum_j u[j]*W1K[j], 8 independent chains.
        v2f tt[8];
        #pragma unroll
        for (int p = 0; p < 8; ++p) tt[p] = b1kp[p];
        #pragma unroll
        for (int jp = 0; jp < 3; ++jp) {
            #pragma unroll
            for (int p = 0; p < 8; ++p) { PK_FMA_LO(tt[p], u2[jp], w1kp[2*jp][p]); }
            #pragma unroll
            for (int p = 0; p < 8; ++p) { PK_FMA_HI(tt[p], u2[jp], w1kp[2*jp+1][p]); }
        }
        // r2[p] = rcp(exp2(tt)+1)  (tanh = 1-2r folded into consts)
        v2f r2[8];
        #pragma unroll
        for (int p = 0; p < 8; ++p) {
            v2f e;
            e.x = __builtin_amdgcn_exp2f(tt[p].x);
            e.y = __builtin_amdgcn_exp2f(tt[p].y);
            e += (v2f){1.f, 1.f};
            r2[p].x = __builtin_amdgcn_rcpf(e.x);
            r2[p].y = __builtin_amdgcn_rcpf(e.y);
        }
        // g = u/4 + c2 + sum_i r_i * (-2 Qs[i,:]); two chains:
        // gA: units 0..7 (pairs 0..3, init = u/4 + c2)
        // gB: units 8..15 (pairs 4..7, init = unit8 mul)
        v2f gA0, gA1, gA2, gB0, gB1, gB2;
        gA0 = __builtin_elementwise_fma(u2[0], quarter, c2[0]);
        gA1 = __builtin_elementwise_fma(u2[1], quarter, c2[1]);
        gA2 = __builtin_elementwise_fma(u2[2], quarter, c2[2]);
        PK_MUL_LO(gB0, r2[4], qs2p[8][0]);
        PK_MUL_LO(gB1, r2[4], qs2p[8][1]);
        PK_MUL_LO(gB2, r2[4], qs2p[8][2]);
        #pragma unroll
        for (int p = 0; p < 4; ++p) {
            PK_FMA_LO(gA0, r2[p], qs2p[2*p][0]);
            PK_FMA_LO(gA1, r2[p], qs2p[2*p][1]);
            PK_FMA_LO(gA2, r2[p], qs2p[2*p][2]);
            PK_FMA_HI(gB0, r2[p+4], qs2p[2*p+9 - (p==0 ? 0 : 0)][0]); // p=0: unit9
            PK_FMA_HI(gB1, r2[p+4], qs2p[2*p+9][1]);
            PK_FMA_HI(gB2, r2[p+4], qs2p[2*p+9][2]);
            PK_FMA_HI(gA0, r2[p], qs2p[2*p+1][0]);
            PK_FMA_HI(gA1, r2[p], qs2p[2*p+1][1]);
            PK_FMA_HI(gA2, r2[p], qs2p[2*p+1][2]);
            if (p < 3) {
                PK_FMA_LO(gB0, r2[p+5], qs2p[2*p+10][0]);
                PK_FMA_LO(gB1, r2[p+5], qs2p[2*p+10][1]);
                PK_FMA_LO(gB2, r2[p+5], qs2p[2*p+10][2]);
            }
        }
        // fix the p==0 hack above: it's just qs2p[9][0] — expression is same
        // combine halves -> 6 scalars (butterfly inputs)
        v2f h0 = gA0 + gB0, h1 = gA1 + gB1, h2 = gA2 + gB2;
        float a0 = h0.x, a1 = h0.y, a2 = h1.x, a3 = h1.y, a4 = h2.x, a5 = h2.y;
        // allreduce over the 4-lane quad: xor1, xor2 (quad_perm DPP).
        // 6 chains interleaved -> >=5 instrs between dependent stages.
        asm("s_nop 1\n\t"
            "v_add_f32_dpp %0, %0, %0 quad_perm:[1,0,3,2] row_mask:0xf bank_mask:0xf bound_ctrl:0\n\t"
            "v_add_f32_dpp %1, %1, %1 quad_perm:[1,0,3,2] row_mask:0xf bank_mask:0xf bound_ctrl:0\n\t"
            "v_add_f32_dpp %2, %2, %2 quad_perm:[1,0,3,2] row_mask:0xf bank_mask:0xf bound_ctrl:0\n\t"
            "v_add_f32_dpp %3, %3, %3 quad_perm:[1,0,3,2] row_mask:0xf bank_mask:0xf bound_ctrl:0\n\t"
            "v_add_f32_dpp %4, %4, %4 quad_perm:[1,0,3,2] row_mask:0xf bank_mask:0xf bound_ctrl:0\n\t"
            "v_add_f32_dpp %5, %5, %5 quad_perm:[1,0,3,2] row_mask:0xf bank_mask:0xf bound_ctrl:0\n\t"
            "v_add_f32_dpp %0, %0, %0 quad_perm:[2,3,0,1] row_mask:0xf bank_mask:0xf bound_ctrl:0\n\t"
            "v_add_f32_dpp %1, %1, %1 quad_perm:[2,3,0,1] row_mask:0xf bank_mask:0xf bound_ctrl:0\n\t"
            "v_add_f32_dpp %2, %2, %2 quad_perm:[2,3,0,1] row_mask:0xf bank_mask:0xf bound_ctrl:0\n\t"
            "v_add_f32_dpp %3, %3, %3 quad_perm:[2,3,0,1] row_mask:0xf bank_mask:0xf bound_ctrl:0\n\t"
            "v_add_f32_dpp %4, %4, %4 quad_perm:[2,3,0,1] row_mask:0xf bank_mask:0xf bound_ctrl:0\n\t"
            "v_add_f32_dpp %5, %5, %5 quad_perm:[2,3,0,1] row_mask:0xf bank_mask:0xf bound_ctrl:0\n\t"
            : "+v"(a0), "+v"(a1), "+v"(a2), "+v"(a3), "+v"(a4), "+v"(a5));
        u2[0].x = __builtin_amdgcn_fmed3f(a0, 0.f, 1.f);
        u2[0].y = __builtin_amdgcn_fmed3f(a1, 0.f, 1.f);
        u2[1].x = __builtin_amdgcn_fmed3f(a2, 0.f, 1.f);
        u2[1].y = __builtin_amdgcn_fmed3f(a3, 0.f, 1.f);
        u2[2].x = __builtin_amdgcn_fmed3f(a4, 0.f, 1.f);
        u2[2].y = __builtin_amdgcn_fmed3f(a5, 0.f, 1.f);
    }

    if (live && sub == 0) {
        float* o = out + s * 6;
        o[0] = u2[0].x; o[1] = u2[0].y;
        o[2] = u2[1].x; o[3] = u2[1].y;
        o[4] = u2[2].x; o[5] = u2[2].y;
    }
}

extern "C" void kernel_launch(void* const* d_in, const int* in_sizes, int n_in,
                              void* d_out, int out_size, void* d_ws, size_t ws_size,
                              hipStream_t stream)
{
    const float* spec = (const float*)d_in[0];  // (B,40)
    const float* W1   = (const float*)d_in[1];  // (6,64)
    const float* b1   = (const float*)d_in[2];  // (64,)
    const float* W2   = (const float*)d_in[3];  // (64,40)
    const float* b2   = (const float*)d_in[4];  // (40,)
    const float* R    = (const float*)d_in[5];  // (8,40)
    int batch = in_sizes[0] / 40;

    int threads = batch * 4;
    int blocks  = (threads + 255) / 256;
    hipLaunchKernelGGL(solve_k, dim3(blocks), dim3(256), 0, stream,
                       spec, W1, b1, W2, b2, R, (float*)d_out, batch);
}